// Round 15
// baseline (5864.985 us; speedup 1.0000x reference)
//
#include <hip/hip_runtime.h>

typedef unsigned char u8;
typedef unsigned short u16;
typedef unsigned int u32;
typedef unsigned long long u64;
typedef short short8 __attribute__((ext_vector_type(8)));
typedef __bf16 bf16x8 __attribute__((ext_vector_type(8)));
typedef float f32x4 __attribute__((ext_vector_type(4)));
typedef float f32x2 __attribute__((ext_vector_type(2)));
typedef long longx2 __attribute__((ext_vector_type(2)));

#define DEV static __device__ __forceinline__

// ---------------------------------------------------------------- params
struct Params {
  const float *x, *eps;
  const float *Wih_ef, *Whh_ef, *bih_ef, *bhh_ef;
  const float *Wih_eb, *Whh_eb, *bih_eb, *bhh_eb;
  const float *W_mu0, *b_mu0, *W_lv0, *b_lv0;
  const float *Wih_c, *Whh_c, *bih_c, *bhh_c;
  const float *W_cmu, *b_cmu, *W_clv, *b_clv;
  const float *Wih_g, *Whh_g, *bih_g, *bhh_g;
  const float *W_f, *b_f, *W_r, *b_r;
  // workspace (weights FRAGMENT-LINEAR swizzled)
  u8  *Xf8;                 // [T][B][256] fp8 (fallback enc path only)
  u16 *ebf;                 // eps swizzled
  u16 *wihcbf, *wihefbf, *wihebbf;   // [768][256] bf16 (k_gx A matrices)
  float *bfc;               // [768] ctrl fused bias
  float *bfe;               // [2][768] enc fused bias
  u8 *wihef8, *whhef8, *wiheb8, *whheb8;    // enc fp8, swizzled K=256
  u8 *whhc8, *whhg8;                        // cg fp8, swizzled K=256
  u8 *wcomb8;                               // (Wcf @ W_f) fp8, swizzled K=256
  u8 *wihg8;                                // swizzled K=64
  u8 *wf8, *wcmu8, *wclv8;                  // swizzled (R=64)
  u16 *wrbf;                                // [256][64] bf16 (k_post)
  float *foldc;             // [768] Wcf @ b_f
  float *cbn;               // [256] bhh_c n-gate
  float *ebn;               // [2][256] bhh_e n-gate
  float *gb;                // [4][256] gen biases
  float *hdb;               // [128]
  float *fb2;               // [64]
  float *eb;                // [2][4][256] enc biases (fallback)
  float *henc;              // [2*256][256]
  float *klacc;             // [16]
  float *klics;             // [32]
  u8 *Gxc;                  // parked in rates region
  u8 *Gxe;                  // [dir] (ws, optional)
  int useGxe;
  float *out;
};

constexpr size_t RATES_N = 33554432ull;
constexpr size_t FOUT    = RATES_N + 2ull;
constexpr size_t GXE_D   = 100663296ull;

// ---------------------------------------------------------------- scalar helpers
DEV u16 f2bf(float x) {
  unsigned u = __builtin_bit_cast(unsigned, x);
  u = (u + 0x7FFFu + ((u >> 16) & 1u)) >> 16;
  return (u16)u;
}
DEV float bf2f(u32 s) { return __builtin_bit_cast(float, s << 16); }
DEV unsigned f2e4m3(float x) {
  unsigned u = __builtin_bit_cast(unsigned, x);
  unsigned s = (u >> 24) & 0x80u;
  float ax = __builtin_bit_cast(float, u & 0x7FFFFFFFu);
  if (ax > 448.f) return s | 0x7E;
  if (ax < 0.0009765625f) return s;
  if (ax < 0.015625f) {
    int m = (int)rintf(ax * 512.f);
    if (m >= 8) return s | 0x08;
    return s | (unsigned)m;
  }
  unsigned au = __builtin_bit_cast(unsigned, ax);
  int E = (int)(au >> 23) - 127;
  unsigned m = au & 0x7FFFFFu;
  unsigned r = (m + 0x7FFFFu + ((m >> 20) & 1u)) >> 20;
  if (r >= 8) { r = 0; ++E; if (E > 8) return s | 0x7E; }
  return s | ((unsigned)(E + 7) << 3) | r;
}
DEV float e4m3tof(unsigned b) {
  unsigned s = (b & 0x80u) << 24;
  unsigned e = (b >> 3) & 15u, m = b & 7u;
  float v;
  if (e) v = __builtin_bit_cast(float, ((e + 120u) << 23) | (m << 20));
  else   v = (float)m * 0.001953125f;
  return __builtin_bit_cast(float, __builtin_bit_cast(unsigned, v) | s);
}
template <bool HI>
DEV unsigned pk2fp8(float a, float b, unsigned old) {
#if __has_builtin(__builtin_amdgcn_cvt_pk_fp8_f32)
  return (unsigned)__builtin_amdgcn_cvt_pk_fp8_f32(a, b, (int)old, HI);
#else
  unsigned p = f2e4m3(a) | (f2e4m3(b) << 8);
  return HI ? ((old & 0xFFFFu) | (p << 16)) : ((old & 0xFFFF0000u) | p);
#endif
}
template <bool HI>
DEV f32x2 pkf32(unsigned w) {
#if __has_builtin(__builtin_amdgcn_cvt_pk_f32_fp8)
  return __builtin_amdgcn_cvt_pk_f32_fp8((int)w, HI);
#else
  unsigned h = HI ? (w >> 16) : w;
  f32x2 r; r[0] = e4m3tof(h & 255u); r[1] = e4m3tof((h >> 8) & 255u); return r;
#endif
}
DEV float sigm(float x) { return 1.f / (1.f + __expf(-x)); }
DEV float ftanh(float x) { float t = __expf(2.f * x); return 1.f - 2.f / (t + 1.f); }
DEV float gru_h(float pr, float pz, float pin, float phn, float hp) {
  float r = sigm(pr), z = sigm(pz);
  float n = ftanh(pin + r * phn);
  return (1.f - z) * n + z * hp;
}
DEV u64 pack8f8(const float* s) {
  u64 p = 0;
  #pragma unroll
  for (int e = 0; e < 8; ++e) p |= (u64)f2e4m3(s[e]) << (8 * e);
  return p;
}

// ---------------------------------------------------------------- MFMA helpers
DEV f32x4 MFMA(short8 a, short8 b, f32x4 c) {
  return __builtin_amdgcn_mfma_f32_16x16x32_bf16(
      __builtin_bit_cast(bf16x8, a), __builtin_bit_cast(bf16x8, b), c, 0, 0, 0);
}
DEV f32x4 mfma8(long a, long b, f32x4 c) {
  return __builtin_amdgcn_mfma_f32_16x16x32_fp8_fp8(a, b, c, 0, 0, 0);
}
DEV short8 ldfrag(const u16* p0, int stride) {
  const int l = threadIdx.x & 63;
  const u16* p = p0 + (size_t)(l & 15) * stride + ((l >> 4) << 3);
  return *reinterpret_cast<const short8*>(p);
}
DEV short8 ldfrag_f32(const float* p0, int stride) {
  const int l = threadIdx.x & 63;
  const float* p = p0 + (size_t)(l & 15) * stride + ((l >> 4) << 3);
  f32x4 a = *reinterpret_cast<const f32x4*>(p);
  f32x4 b = *reinterpret_cast<const f32x4*>(p + 4);
  short8 r;
  r[0]=(short)f2bf(a[0]); r[1]=(short)f2bf(a[1]); r[2]=(short)f2bf(a[2]); r[3]=(short)f2bf(a[3]);
  r[4]=(short)f2bf(b[0]); r[5]=(short)f2bf(b[1]); r[6]=(short)f2bf(b[2]); r[7]=(short)f2bf(b[3]);
  return r;
}
// fragment-linear readers: global and LDS share the same offset math
DEV longx2 ldws2(const u8* w, int tile, int p) {
  return *(const longx2*)(w + ((size_t)tile << 12) + (p << 10) + ((threadIdx.x & 63) << 4));
}
DEV longx2 ldws64x(const u8* w, int tile) {
  return *(const longx2*)(w + ((size_t)tile << 10) + ((threadIdx.x & 63) << 4));
}
// ---------- fragment-native LDS state layout ----------
DEV int fragoff(int row, int jb) { return jb * 128 + ((row ^ (jb & 15)) << 3); }
DEV long ldsF(const u8* m, int kk) {
  int l = threadIdx.x & 63;
  int jb = kk * 4 + (l >> 4);
  return *(const long*)(m + fragoff(l & 15, jb));
}
DEV void stF(u8* m, int row, int col, unsigned v) {
  *(unsigned*)(m + fragoff(row, col >> 3) + (col & 7)) = v;
}
// bf16 helpers for k_gx
DEV short8 ldsB16(const u8* m, int r0, int kk) {
  int l = threadIdx.x & 63;
  int row = r0 + (l & 15);
  int off = row * 512 + kk * 64 + ((l >> 4) << 4);
  off ^= (row & 7) << 4;
  return *(const short8*)(m + off);
}
DEV void stage16(u8* dst, const u8* src, int nbytes) {
  for (int i = threadIdx.x * 16; i < nbytes; i += blockDim.x * 16) {
    int row = i >> 9;
    int off = i ^ ((row & 7) << 4);
    *(f32x4*)(dst + off) = *(const f32x4*)(src + i);
  }
}
DEV void stageLin(u8* dst, const u8* src, int nbytes) {
  for (int i = threadIdx.x * 16; i < nbytes; i += 512 * 16)
    *(f32x4*)(dst + i) = *(const f32x4*)(src + i);
}

// ---------------------------------------------------------------- k_init
__global__ __launch_bounds__(256) void k_init(Params P) {
  const size_t g  = (size_t)blockIdx.x * 256 + threadIdx.x;
  const size_t gs = (size_t)gridDim.x * 256;
  if (!P.useGxe) {
    for (size_t i = g; i < 4194304ull; i += gs) {
      size_t flat = i << 3;
      int b = (int)(flat >> 17);
      int rem = (int)(flat & 131071);
      int t = rem >> 8, d = rem & 255;
      *(u64*)(P.Xf8 + (((size_t)t * 256 + b) << 8) + d) = pack8f8(P.x + flat);
    }
  }
  for (size_t o = g; o < 1048576ull; o += gs) {
    int l = (int)(o & 63), k2 = (int)((o >> 6) & 1);
    int bt = (int)((o >> 7) & 15), t = (int)(o >> 11);
    int row = bt * 16 + (l & 15), col = k2 * 32 + ((l >> 4) << 3);
    const float* s = P.eps + ((size_t)t * 256 + row) * 64 + col;
    f32x4 v0 = *(const f32x4*)s, v1 = *(const f32x4*)(s + 4);
    short8 ob;
    ob[0]=(short)f2bf(v0[0]); ob[1]=(short)f2bf(v0[1]); ob[2]=(short)f2bf(v0[2]); ob[3]=(short)f2bf(v0[3]);
    ob[4]=(short)f2bf(v1[0]); ob[5]=(short)f2bf(v1[1]); ob[6]=(short)f2bf(v1[2]); ob[7]=(short)f2bf(v1[3]);
    *(short8*)((u8*)P.ebf + o * 16) = ob;
  }
  const int gi = (int)g, gsi = (int)gs;
  for (int i = gi; i < 24576; i += gsi) {
    int l = i & 63, kk = (i >> 6) & 7, tile = i >> 9;
    int row = tile * 16 + (l & 15), col = kk * 32 + ((l >> 4) << 3);
    size_t so = (size_t)row * 256 + col;
    size_t db = ((size_t)tile << 12) + ((kk >> 1) << 10) + (l << 4) + ((kk & 1) << 3);
    *(u64*)(P.whhc8  + db) = pack8f8(P.Whh_c  + so);
    *(u64*)(P.whhg8  + db) = pack8f8(P.Whh_g  + so);
    *(u64*)(P.wihef8 + db) = pack8f8(P.Wih_ef + so);
    *(u64*)(P.whhef8 + db) = pack8f8(P.Whh_ef + so);
    *(u64*)(P.wiheb8 + db) = pack8f8(P.Wih_eb + so);
    *(u64*)(P.whheb8 + db) = pack8f8(P.Whh_eb + so);
  }
  // W_comb = Wcf @ W_f (f32 accumulate), fp8 swizzled; foldc = Wcf @ b_f
  for (int i = gi; i < 196608; i += gsi) {
    int r = i >> 8, c = i & 255;
    float acc = 0.f;
    const float* wr = P.Wih_c + (size_t)r * 320 + 256;
    #pragma unroll 4
    for (int l = 0; l < 64; ++l) acc += wr[l] * P.W_f[l * 256 + c];
    int tile = r >> 4, row15 = r & 15;
    int kk = c >> 5, lh = (c >> 3) & 3, e = c & 7;
    int lane = lh * 16 + row15;
    size_t db = ((size_t)tile << 12) + ((size_t)(kk >> 1) << 10) + (lane << 4) + ((kk & 1) << 3) + e;
    P.wcomb8[db] = (u8)f2e4m3(acc);
  }
  for (int i = gi; i < 768; i += gsi) {
    float acc = 0.f;
    const float* wr = P.Wih_c + (size_t)i * 320 + 256;
    for (int l = 0; l < 64; ++l) acc += wr[l] * P.b_f[l];
    P.foldc[i] = acc;
  }
  for (int i = gi; i < 2048; i += gsi) {
    int l = i & 63, kk = (i >> 6) & 7, tile = i >> 9;
    int row = tile * 16 + (l & 15), col = kk * 32 + ((l >> 4) << 3);
    size_t so = (size_t)row * 256 + col;
    size_t db = ((size_t)tile << 12) + ((kk >> 1) << 10) + (l << 4) + ((kk & 1) << 3);
    *(u64*)(P.wf8   + db) = pack8f8(P.W_f   + so);
    *(u64*)(P.wcmu8 + db) = pack8f8(P.W_cmu + so);
    *(u64*)(P.wclv8 + db) = pack8f8(P.W_clv + so);
  }
  for (int i = gi; i < 6144; i += gsi) {
    int l = i & 63, k2 = (i >> 6) & 1, tile = i >> 7;
    int row = tile * 16 + (l & 15), col = k2 * 32 + ((l >> 4) << 3);
    size_t db = ((size_t)tile << 10) + (l << 4) + (k2 << 3);
    *(u64*)(P.wihg8  + db) = pack8f8(P.Wih_g + (size_t)row * 64 + col);
  }
  for (int i = gi; i < 196608; i += gsi) {
    int r = i >> 8, c = i & 255;
    P.wihcbf[i]  = f2bf(P.Wih_c[r * 320 + c]);
    P.wihefbf[i] = f2bf(P.Wih_ef[i]);
    P.wihebbf[i] = f2bf(P.Wih_eb[i]);
  }
  for (int i = gi; i < 16384; i += gsi) P.wrbf[i] = f2bf(P.W_r[i]);
  for (int i = gi; i < 768; i += gsi) {
    P.bfc[i] = P.bih_c[i] + (i < 512 ? P.bhh_c[i] : 0.f);
    P.bfe[i]       = P.bih_ef[i] + (i < 512 ? P.bhh_ef[i] : 0.f);
    P.bfe[768 + i] = P.bih_eb[i] + (i < 512 ? P.bhh_eb[i] : 0.f);
  }
  for (int i = gi; i < 256; i += gsi) {
    P.cbn[i] = P.bhh_c[512 + i];
    P.ebn[i]       = P.bhh_ef[512 + i];
    P.ebn[256 + i] = P.bhh_eb[512 + i];
    P.gb[i]        = P.bih_g[i] + P.bhh_g[i];
    P.gb[256 + i]  = P.bih_g[256 + i] + P.bhh_g[256 + i];
    P.gb[512 + i]  = P.bih_g[512 + i];
    P.gb[768 + i]  = P.bhh_g[512 + i];
    P.eb[i]        = P.bih_ef[i] + P.bhh_ef[i];
    P.eb[256 + i]  = P.bih_ef[256 + i] + P.bhh_ef[256 + i];
    P.eb[512 + i]  = P.bih_ef[512 + i];
    P.eb[768 + i]  = P.bhh_ef[512 + i];
    P.eb[1024 + i] = P.bih_eb[i] + P.bhh_eb[i];
    P.eb[1280 + i] = P.bih_eb[256 + i] + P.bhh_eb[256 + i];
    P.eb[1536 + i] = P.bih_eb[512 + i];
    P.eb[1792 + i] = P.bhh_eb[512 + i];
  }
  for (int i = gi; i < 128; i += gsi) P.hdb[i] = (i < 64) ? P.b_cmu[i] : P.b_clv[i - 64];
  for (int i = gi; i < 64; i += gsi)  P.fb2[i] = P.b_f[i];
}

// ---------------------------------------------------------------- k_gx : one block does all (up to 3) matrices; x staged once
__global__ __launch_bounds__(512, 2) void k_gx(Params P) {
  extern __shared__ char smem[];
  u8* sA = (u8*)smem;
  u8* sB = sA + 65536;
  const int nc = blockIdx.x % 6;
  const int tb = blockIdx.x / 6;
  const int t = tb >> 1, bh = tb & 1;
  for (int i = threadIdx.x * 8; i < 32768; i += 512 * 8) {
    int r = i >> 8, c = i & 255;
    const float* s = P.x + ((size_t)(bh * 128 + r) * 512 + t) * 256 + c;
    f32x4 v0 = *(const f32x4*)s, v1 = *(const f32x4*)(s + 4);
    short8 o;
    o[0]=(short)f2bf(v0[0]); o[1]=(short)f2bf(v0[1]); o[2]=(short)f2bf(v0[2]); o[3]=(short)f2bf(v0[3]);
    o[4]=(short)f2bf(v1[0]); o[5]=(short)f2bf(v1[1]); o[6]=(short)f2bf(v1[2]); o[7]=(short)f2bf(v1[3]);
    int off = (r * 512 + c * 2) ^ ((r & 7) << 4);
    *(short8*)(sB + off) = o;
  }
  const int lane = threadIdx.x & 63, wid = threadIdx.x >> 6;
  const int rq = (lane >> 4) << 2;
  const int nglob = nc * 128 + wid * 16;
  const int nmm = P.useGxe ? 3 : 1;
  #pragma unroll 1
  for (int mm = 0; mm < nmm; ++mm) {
    const u16* Abf = (mm == 0) ? P.wihcbf : ((mm == 1) ? P.wihefbf : P.wihebbf);
    const float* bias = (mm == 0) ? P.bfc : (P.bfe + (mm - 1) * 768);
    u8* dst = (mm == 0) ? P.Gxc : (P.Gxe + (size_t)(mm - 1) * GXE_D);
    stage16(sA, (const u8*)(Abf + (size_t)nc * 128 * 256), 65536);
    __syncthreads();
    short8 Af[8];
    #pragma unroll
    for (int kk = 0; kk < 8; ++kk) Af[kk] = ldsB16(sA, wid * 16, kk);
    float bq[4];
    #pragma unroll
    for (int q = 0; q < 4; ++q) bq[q] = bias[nglob + rq + q];
    #pragma unroll 1
    for (int bt = 0; bt < 8; ++bt) {
      f32x4 acc = {0.f, 0.f, 0.f, 0.f};
      #pragma unroll
      for (int kk = 0; kk < 8; ++kk)
        acc = MFMA(Af[kk], ldsB16(sB, bt * 16, kk), acc);
      float v0 = acc[0] + bq[0], v1 = acc[1] + bq[1], v2 = acc[2] + bq[2], v3 = acc[3] + bq[3];
      unsigned pw = pk2fp8<false>(v0, v1, 0u); pw = pk2fp8<true>(v2, v3, pw);
      *(u32*)(dst + (((size_t)(t * 16 + bh * 8 + bt) * 48 + (nglob >> 4)) << 8) + (lane << 2)) = pw;
    }
    __syncthreads();
  }
}

// ---------------------------------------------------------------- k_main
// cg: 3 barriers/step. Controller consumes hg_prev via W_comb (factors dep folded).
DEV void cg_role(const Params& P, int blk, char* smem) {
  u8* sWg  = (u8*)smem;                 // 49152 (K=64 gen input weights)
  u8* sWhd = sWg + 49152;               // 32768 (wcmu|wclv)
  u8* hc8  = sWhd + 32768;              // 2*4096
  u8* hg8  = hc8 + 8192;                // 2*4096
  float* sml  = (float*)(hg8 + 8192);   // 8448
  float* sred = sml + 16 * 132;         // 64

  const int lane = threadIdx.x & 63, wid = threadIdx.x >> 6;  // 8 waves
  const int cl = lane & 15, rq = (lane >> 4) << 2;
  const int b0 = blk << 4, j0 = wid << 5, jt = wid << 1;
  const int sel = wid >> 2, l0 = (wid & 3) << 4;

  stageLin(sWg,  P.wihg8,  49152);
  stageLin(sWhd, P.wcmu8, 16384);
  stageLin(sWhd + 16384, P.wclv8, 16384);
  for (int i = threadIdx.x * 4; i < 16384; i += 512 * 4) *(int*)(hc8 + i) = 0;

  f32x4 bnv[2], brv[2], bzv[2], biv[2], bhv2[2];
  f32x4 frv[2], fzv[2], fnv[2];
  #pragma unroll
  for (int c2 = 0; c2 < 2; ++c2) {
    int j = j0 + c2 * 16 + rq;
    bnv[c2]  = *(const f32x4*)(P.cbn + j);
    brv[c2]  = *(const f32x4*)(P.gb + j);
    bzv[c2]  = *(const f32x4*)(P.gb + 256 + j);
    biv[c2]  = *(const f32x4*)(P.gb + 512 + j);
    bhv2[c2] = *(const f32x4*)(P.gb + 768 + j);
    frv[c2]  = *(const f32x4*)(P.foldc + j);
    fzv[c2]  = *(const f32x4*)(P.foldc + 256 + j);
    fnv[c2]  = *(const f32x4*)(P.foldc + 512 + j);
  }
  f32x4 hbv = *(const f32x4*)(P.hdb + sel * 64 + l0 + rq);
  f32x4 fbv = {0, 0, 0, 0};
  if (wid < 4) fbv = *(const f32x4*)(P.fb2 + (wid << 4) + rq);

  f32x4 hcM[2] = {{0,0,0,0},{0,0,0,0}};
  f32x4 hgM[2] = {{0,0,0,0},{0,0,0,0}};
  float klv = 0.f;
  __syncthreads();

  #pragma unroll 1
  for (int t = 0; t < 512; ++t) {
    const int cur = t & 1, prv = cur ^ 1;
    u8 *hcP = hc8 + prv * 4096, *hcC = hc8 + cur * 4096;
    u8 *hgP = hg8 + prv * 4096, *hgC = hg8 + cur * 4096;
    const float sc = (t == 0) ? 0.f : 1.f;
    // early coalesced Gxc + eps
    u32 gx[6];
    { const u8* gp = P.Gxc + (((size_t)(t * 16 + blk) * 48) << 8) + (lane << 2);
      #pragma unroll
      for (int c2 = 0; c2 < 2; ++c2)
        #pragma unroll
        for (int g3 = 0; g3 < 3; ++g3)
          gx[c2 * 3 + g3] = *(const u32*)(gp + ((g3 * 16 + jt + c2) << 8));
    }
    short8 ee0 = *(const short8*)((const u8*)P.ebf + (((size_t)(t * 16 + blk) * 2 + 0) << 10) + lane * 16);
    short8 ee1 = *(const short8*)((const u8*)P.ebf + (((size_t)(t * 16 + blk) * 2 + 1) << 10) + lane * 16);
    // ---- P1: controller GRU (whhc·hc + wcomb·hg_prev) ----
    long hf[8], hgv[8];
    #pragma unroll
    for (int kk = 0; kk < 8; ++kk) { hf[kk] = ldsF(hcP, kk); hgv[kk] = ldsF(hgP, kk); }
    #pragma unroll
    for (int c2 = 0; c2 < 2; ++c2) {
      longx2 w0[4], w1[4], w2[4];
      #pragma unroll
      for (int p = 0; p < 4; ++p) {
        w0[p] = ldws2(P.whhc8,      jt + c2, p);
        w1[p] = ldws2(P.whhc8, 16 + jt + c2, p);
        w2[p] = ldws2(P.whhc8, 32 + jt + c2, p);
      }
      longx2 m0[4], m1[4], m2[4];
      #pragma unroll
      for (int p = 0; p < 4; ++p) {
        m0[p] = ldws2(P.wcomb8,      jt + c2, p);
        m1[p] = ldws2(P.wcomb8, 16 + jt + c2, p);
        m2[p] = ldws2(P.wcomb8, 32 + jt + c2, p);
      }
      f32x4 ar = {0,0,0,0}, az = {0,0,0,0}, ai = {0,0,0,0}, ah = {0,0,0,0};
      #pragma unroll
      for (int p = 0; p < 4; ++p) {
        ar = mfma8(w0[p].x, hf[2*p], ar);  ar = mfma8(w0[p].y, hf[2*p+1], ar);
        az = mfma8(w1[p].x, hf[2*p], az);  az = mfma8(w1[p].y, hf[2*p+1], az);
        ah = mfma8(w2[p].x, hf[2*p], ah);  ah = mfma8(w2[p].y, hf[2*p+1], ah);
        ar = mfma8(m0[p].x, hgv[2*p], ar); ar = mfma8(m0[p].y, hgv[2*p+1], ar);
        az = mfma8(m1[p].x, hgv[2*p], az); az = mfma8(m1[p].y, hgv[2*p+1], az);
        ai = mfma8(m2[p].x, hgv[2*p], ai); ai = mfma8(m2[p].y, hgv[2*p+1], ai);
      }
      f32x2 rlo = pkf32<false>(gx[c2*3+0]), rhi = pkf32<true>(gx[c2*3+0]);
      f32x2 zlo = pkf32<false>(gx[c2*3+1]), zhi = pkf32<true>(gx[c2*3+1]);
      f32x2 nlo = pkf32<false>(gx[c2*3+2]), nhi = pkf32<true>(gx[c2*3+2]);
      f32x4 bn = bnv[c2];
      float h0 = gru_h(ar[0]+rlo[0]+sc*frv[c2][0], az[0]+zlo[0]+sc*fzv[c2][0],
                       ai[0]+nlo[0]+sc*fnv[c2][0], ah[0]+bn[0], hcM[c2][0]);
      float h1 = gru_h(ar[1]+rlo[1]+sc*frv[c2][1], az[1]+zlo[1]+sc*fzv[c2][1],
                       ai[1]+nlo[1]+sc*fnv[c2][1], ah[1]+bn[1], hcM[c2][1]);
      float h2 = gru_h(ar[2]+rhi[0]+sc*frv[c2][2], az[2]+zhi[0]+sc*fzv[c2][2],
                       ai[2]+nhi[0]+sc*fnv[c2][2], ah[2]+bn[2], hcM[c2][2]);
      float h3 = gru_h(ar[3]+rhi[1]+sc*frv[c2][3], az[3]+zhi[1]+sc*fzv[c2][3],
                       ai[3]+nhi[1]+sc*fnv[c2][3], ah[3]+bn[3], hcM[c2][3]);
      hcM[c2][0] = h0; hcM[c2][1] = h1; hcM[c2][2] = h2; hcM[c2][3] = h3;
      unsigned pw = pk2fp8<false>(h0, h1, 0u); pw = pk2fp8<true>(h2, h3, pw);
      stF(hcC, cl, j0 + c2 * 16 + rq, pw);
    }
    // cross-barrier prefetch of P3's whhg (c2=0)
    longx2 pg0[4], pg1[4], pg2[4];
    #pragma unroll
    for (int p = 0; p < 4; ++p) {
      pg0[p] = ldws2(P.whhg8,      jt, p);
      pg1[p] = ldws2(P.whhg8, 16 + jt, p);
      pg2[p] = ldws2(P.whhg8, 32 + jt, p);
    }
    __syncthreads();                                    // B1
    // ---- P2: heads -> sml ----
    { long hcv[8];
      #pragma unroll
      for (int kk = 0; kk < 8; ++kk) hcv[kk] = ldsF(hcC, kk);
      f32x4 am = {0,0,0,0};
      #pragma unroll
      for (int p = 0; p < 4; ++p) {
        longx2 wp = ldws2(sWhd + sel * 16384, wid & 3, p);
        am = mfma8(wp.x, hcv[2*p], am);
        am = mfma8(wp.y, hcv[2*p+1], am);
      }
      am += hbv;
      *(f32x4*)(sml + cl * 132 + sel * 64 + l0 + rq) = am;
    }
    __syncthreads();                                    // B2
    // ---- P3: u + generator GRU ----
    long U[2];
    { const float* ml = sml + cl * 132;
      const int kh = (lane >> 4) << 3;
      #pragma unroll
      for (int k2 = 0; k2 < 2; ++k2) {
        f32x4 mu0 = *(const f32x4*)(ml + k2 * 32 + kh);
        f32x4 mu1 = *(const f32x4*)(ml + k2 * 32 + kh + 4);
        f32x4 lv0 = *(const f32x4*)(ml + 64 + k2 * 32 + kh);
        f32x4 lv1 = *(const f32x4*)(ml + 64 + k2 * 32 + kh + 4);
        short8 ev = k2 ? ee1 : ee0;
        float uu[8];
        #pragma unroll
        for (int e = 0; e < 4; ++e) {
          float epv = bf2f((u32)(u16)ev[e]);
          uu[e] = mu0[e] + epv * __expf(0.5f * lv0[e]);
        }
        #pragma unroll
        for (int e = 0; e < 4; ++e) {
          float epv = bf2f((u32)(u16)ev[4 + e]);
          uu[4 + e] = mu1[e] + epv * __expf(0.5f * lv1[e]);
        }
        unsigned pa = pk2fp8<false>(uu[0], uu[1], 0u); pa = pk2fp8<true>(uu[2], uu[3], pa);
        unsigned pb = pk2fp8<false>(uu[4], uu[5], 0u); pb = pk2fp8<true>(uu[6], uu[7], pb);
        U[k2] = (long)(((u64)pb << 32) | (u64)pa);
      }
    }
    long hg[8];
    #pragma unroll
    for (int kk = 0; kk < 8; ++kk) hg[kk] = ldsF(hgP, kk);
    #pragma unroll
    for (int c2 = 0; c2 < 2; ++c2) {
      longx2 g0[4], g1[4], g2[4];
      if (c2 == 0) {
        #pragma unroll
        for (int p = 0; p < 4; ++p) { g0[p] = pg0[p]; g1[p] = pg1[p]; g2[p] = pg2[p]; }
      } else {
        #pragma unroll
        for (int p = 0; p < 4; ++p) {
          g0[p] = ldws2(P.whhg8,      jt + 1, p);
          g1[p] = ldws2(P.whhg8, 16 + jt + 1, p);
          g2[p] = ldws2(P.whhg8, 32 + jt + 1, p);
        }
      }
      longx2 u0 = ldws64x(sWg,      jt + c2);
      longx2 u1 = ldws64x(sWg, 16 + jt + c2);
      longx2 u2 = ldws64x(sWg, 32 + jt + c2);
      f32x4 gr = {0,0,0,0}, gz = {0,0,0,0}, gi = {0,0,0,0}, gh = {0,0,0,0};
      #pragma unroll
      for (int p = 0; p < 4; ++p) {
        gr = mfma8(g0[p].x, hg[2*p], gr);  gr = mfma8(g0[p].y, hg[2*p+1], gr);
        gz = mfma8(g1[p].x, hg[2*p], gz);  gz = mfma8(g1[p].y, hg[2*p+1], gz);
        gh = mfma8(g2[p].x, hg[2*p], gh);  gh = mfma8(g2[p].y, hg[2*p+1], gh);
      }
      gr = mfma8(u0.x, U[0], gr); gr = mfma8(u0.y, U[1], gr);
      gz = mfma8(u1.x, U[0], gz); gz = mfma8(u1.y, U[1], gz);
      gi = mfma8(u2.x, U[0], gi); gi = mfma8(u2.y, U[1], gi);
      float h0 = gru_h(gr[0]+brv[c2][0], gz[0]+bzv[c2][0], gi[0]+biv[c2][0], gh[0]+bhv2[c2][0], hgM[c2][0]);
      float h1 = gru_h(gr[1]+brv[c2][1], gz[1]+bzv[c2][1], gi[1]+biv[c2][1], gh[1]+bhv2[c2][1], hgM[c2][1]);
      float h2 = gru_h(gr[2]+brv[c2][2], gz[2]+bzv[c2][2], gi[2]+biv[c2][2], gh[2]+bhv2[c2][2], hgM[c2][2]);
      float h3 = gru_h(gr[3]+brv[c2][3], gz[3]+bzv[c2][3], gi[3]+biv[c2][3], gh[3]+bhv2[c2][3], hgM[c2][3]);
      hgM[c2][0] = h0; hgM[c2][1] = h1; hgM[c2][2] = h2; hgM[c2][3] = h3;
      unsigned pw = pk2fp8<false>(h0, h1, 0u); pw = pk2fp8<true>(h2, h3, pw);
      stF(hgC, cl, j0 + c2 * 16 + rq, pw);
    }
    __syncthreads();                                    // B3
    // ---- P4: factors output + KL (no in-loop consumer; B4 eliminated) ----
    if (wid < 4) {
      long hgv2[8];
      #pragma unroll
      for (int kk = 0; kk < 8; ++kk) hgv2[kk] = ldsF(hgC, kk);
      f32x4 af = {0,0,0,0};
      #pragma unroll
      for (int p = 0; p < 4; ++p) {
        longx2 wp = ldws2(P.wf8, wid, p);
        af = mfma8(wp.x, hgv2[2*p], af);
        af = mfma8(wp.y, hgv2[2*p+1], af);
      }
      af += fbv;
      float* fo = P.out + FOUT + (size_t)(b0 + cl) * 32768 + (size_t)t * 64 + wid * 16 + rq;
      f32x2 lo = {af[0], af[1]}, hi2 = {af[2], af[3]};
      *(f32x2*)fo = lo;
      *(f32x2*)(fo + 2) = hi2;
    } else {
      #pragma unroll
      for (int e = 0; e < 4; ++e) {
        int p = ((wid - 4) * 64 + lane) * 4 + e;
        int row = p >> 6, l = p & 63;
        float mu = sml[row * 132 + l], lv = sml[row * 132 + 64 + l];
        klv += __expf(lv) + mu * mu - 1.f - lv;
      }
    }
    // no B4: next P1 reads hc/hg (published at B1/B3); sml rewrite guarded by B1(t+1)
  }
  if (wid >= 4) {
    float v = klv;
    v += __shfl_down(v, 32); v += __shfl_down(v, 16); v += __shfl_down(v, 8);
    v += __shfl_down(v, 4);  v += __shfl_down(v, 2);  v += __shfl_down(v, 1);
    if (lane == 0) sred[wid] = v;
  }
  __syncthreads();
  if (threadIdx.x == 0) P.klacc[blk] = sred[4] + sred[5] + sred[6] + sred[7];
}

// enc: Whh gates r,z LDS-persistent; gate n streamed.
template <bool GXE>
DEV void enc_role(const Params& P, int dir, int b0, char* smem) {
  u8* sWhh = (u8*)smem;                 // 131072
  u8* h8   = sWhh + 131072;             // 2*4096
  u8* sx   = h8 + 8192;                 // 2*4096 (fallback only)
  const int lane = threadIdx.x & 63, wid = threadIdx.x >> 6;
  const int cl = lane & 15, rq = (lane >> 4) << 2;
  const int j0 = wid << 5, jt = wid << 1;
  const int btile = b0 >> 4;
  const u8* wihG = dir ? P.wiheb8 : P.wihef8;
  const u8* whhG = dir ? P.whheb8 : P.whhef8;
  stageLin(sWhh, whhG, 131072);
  for (int i = threadIdx.x * 4; i < 8192; i += 512 * 4) *(int*)(h8 + i) = 0;
  f32x4 bnv[2], brv[2], bzv[2], biv[2], bhv2[2];
  #pragma unroll
  for (int c2 = 0; c2 < 2; ++c2) {
    int j = j0 + c2 * 16 + rq;
    if (GXE) {
      bnv[c2] = *(const f32x4*)(P.ebn + dir * 256 + j);
    } else {
      const float* ebt = P.eb + dir * 1024;
      brv[c2]  = *(const f32x4*)(ebt + j);
      bzv[c2]  = *(const f32x4*)(ebt + 256 + j);
      biv[c2]  = *(const f32x4*)(ebt + 512 + j);
      bhv2[c2] = *(const f32x4*)(ebt + 768 + j);
    }
  }
  f32x4 heM[2] = {{0,0,0,0},{0,0,0,0}};
  const int ssrc = threadIdx.x * 8;
  if (!GXE) {
    const int t0 = dir ? 511 : 0;
    *(u64*)(sx + fragoff(threadIdx.x >> 5, threadIdx.x & 31)) =
        *(const u64*)(P.Xf8 + (((size_t)t0 * 256 + b0) << 8) + ssrc);
  }
  __syncthreads();

  #pragma unroll 1
  for (int i = 0; i < 512; ++i) {
    const int cur = i & 1, prv = cur ^ 1;
    const int t = dir ? (511 - i) : i;
    u8 *hP = h8 + prv * 4096, *hC = h8 + cur * 4096;
    u32 gx[6];
    u64 xpre = 0;
    const u8* sxc = sx + cur * 4096;
    if (GXE) {
      const u8* gp = P.Gxe + (size_t)dir * GXE_D +
                     (((size_t)(t * 16 + btile) * 48) << 8) + (lane << 2);
      #pragma unroll
      for (int c2 = 0; c2 < 2; ++c2)
        #pragma unroll
        for (int g3 = 0; g3 < 3; ++g3)
          gx[c2 * 3 + g3] = *(const u32*)(gp + ((g3 * 16 + jt + c2) << 8));
    } else {
      if (i < 511) {
        int tn = dir ? (t - 1) : (t + 1);
        xpre = *(const u64*)(P.Xf8 + (((size_t)tn * 256 + b0) << 8) + ssrc);
      }
    }
    long hp[8];
    #pragma unroll
    for (int kk = 0; kk < 8; ++kk) hp[kk] = ldsF(hP, kk);
    #pragma unroll
    for (int c2 = 0; c2 < 2; ++c2) {
      longx2 Hr[4], Hz[4], Hn[4];
      #pragma unroll
      for (int p = 0; p < 4; ++p) {
        Hr[p] = ldws2(sWhh,      jt + c2, p);
        Hz[p] = ldws2(sWhh, 16 + jt + c2, p);
        Hn[p] = ldws2(whhG, 32 + jt + c2, p);
      }
      f32x4 er = {0,0,0,0}, ez = {0,0,0,0}, ei = {0,0,0,0}, eh = {0,0,0,0};
      #pragma unroll
      for (int p = 0; p < 4; ++p) {
        er = mfma8(Hr[p].x, hp[2*p], er);  er = mfma8(Hr[p].y, hp[2*p+1], er);
        ez = mfma8(Hz[p].x, hp[2*p], ez);  ez = mfma8(Hz[p].y, hp[2*p+1], ez);
        eh = mfma8(Hn[p].x, hp[2*p], eh);  eh = mfma8(Hn[p].y, hp[2*p+1], eh);
      }
      if (!GXE) {
        long xv[8];
        #pragma unroll
        for (int kk = 0; kk < 8; ++kk) xv[kk] = ldsF(sxc, kk);
        longx2 Ir[4], Iz[4], In[4];
        #pragma unroll
        for (int p = 0; p < 4; ++p) {
          Ir[p] = ldws2(wihG,      jt + c2, p);
          Iz[p] = ldws2(wihG, 16 + jt + c2, p);
          In[p] = ldws2(wihG, 32 + jt + c2, p);
        }
        #pragma unroll
        for (int p = 0; p < 4; ++p) {
          er = mfma8(Ir[p].x, xv[2*p], er);  er = mfma8(Ir[p].y, xv[2*p+1], er);
          ez = mfma8(Iz[p].x, xv[2*p], ez);  ez = mfma8(Iz[p].y, xv[2*p+1], ez);
          ei = mfma8(In[p].x, xv[2*p], ei);  ei = mfma8(In[p].y, xv[2*p+1], ei);
        }
      }
      float h0, h1, h2, h3;
      if (GXE) {
        f32x2 rlo = pkf32<false>(gx[c2*3+0]), rhi = pkf32<true>(gx[c2*3+0]);
        f32x2 zlo = pkf32<false>(gx[c2*3+1]), zhi = pkf32<true>(gx[c2*3+1]);
        f32x2 nlo = pkf32<false>(gx[c2*3+2]), nhi = pkf32<true>(gx[c2*3+2]);
        f32x4 bn = bnv[c2];
        h0 = gru_h(er[0]+rlo[0], ez[0]+zlo[0], nlo[0], eh[0]+bn[0], heM[c2][0]);
        h1 = gru_h(er[1]+rlo[1], ez[1]+zlo[1], nlo[1], eh[1]+bn[1], heM[c2][1]);
        h2 = gru_h(er[2]+rhi[0], ez[2]+zhi[0], nhi[0], eh[2]+bn[2], heM[c2][2]);
        h3 = gru_h(er[3]+rhi[1], ez[3]+zhi[1], nhi[1], eh[3]+bn[3], heM[c2][3]);
      } else {
        h0 = gru_h(er[0]+brv[c2][0], ez[0]+bzv[c2][0], ei[0]+biv[c2][0], eh[0]+bhv2[c2][0], heM[c2][0]);
        h1 = gru_h(er[1]+brv[c2][1], ez[1]+bzv[c2][1], ei[1]+biv[c2][1], eh[1]+bhv2[c2][1], heM[c2][1]);
        h2 = gru_h(er[2]+brv[c2][2], ez[2]+bzv[c2][2], ei[2]+biv[c2][2], eh[2]+bhv2[c2][2], heM[c2][2]);
        h3 = gru_h(er[3]+brv[c2][3], ez[3]+bzv[c2][3], ei[3]+biv[c2][3], eh[3]+bhv2[c2][3], heM[c2][3]);
      }
      heM[c2][0] = h0; heM[c2][1] = h1; heM[c2][2] = h2; heM[c2][3] = h3;
      unsigned pw = pk2fp8<false>(h0, h1, 0u); pw = pk2fp8<true>(h2, h3, pw);
      stF(hC, cl, j0 + c2 * 16 + rq, pw);
    }
    if (!GXE && i < 511)
      *(u64*)(sx + prv * 4096 + fragoff(threadIdx.x >> 5, threadIdx.x & 31)) = xpre;
    __syncthreads();
  }
  #pragma unroll
  for (int c2 = 0; c2 < 2; ++c2)
    *(f32x4*)(P.henc + (size_t)(dir * 256 + b0 + cl) * 256 + j0 + c2 * 16 + rq) = heM[c2];
}

__global__ __launch_bounds__(512)
__attribute__((amdgpu_waves_per_eu(2, 2)))
void k_main(Params P) {
  extern __shared__ char smem[];
  const int blk = blockIdx.x;
  if (blk < 16) cg_role(P, blk, smem);
  else {
    const int e = blk - 16;
    if (P.useGxe) enc_role<true>(P, e >> 4, (e & 15) << 4, smem);
    else          enc_role<false>(P, e >> 4, (e & 15) << 4, smem);
  }
}

// ---------------------------------------------------------------- k_post
__global__ __launch_bounds__(256) void k_post(Params P) {
  const int blk = blockIdx.x;
  if (blk < 32) {
    __shared__ float red[4];
    float ka = 0.f;
    #pragma unroll 1
    for (int pp = 0; pp < 2; ++pp) {
      int p = blk * 512 + threadIdx.x * 2 + pp;
      int b = p >> 6, l = p & 63;
      float mu = P.b_mu0[l], lv = P.b_lv0[l];
      const float* wm = P.W_mu0 + (size_t)l * 512;
      const float* wl = P.W_lv0 + (size_t)l * 512;
      const float* h0 = P.henc + (size_t)b * 256;
      const float* h1 = P.henc + (size_t)(256 + b) * 256;
      #pragma unroll 4
      for (int k = 0; k < 256; ++k) {
        float hf = h0[k], hb = h1[k];
        mu += hf * wm[k] + hb * wm[256 + k];
        lv += hf * wl[k] + hb * wl[256 + k];
      }
      ka += __expf(lv) + mu * mu - 1.f - lv;
    }
    const int lane = threadIdx.x & 63, wid = threadIdx.x >> 6;
    ka += __shfl_down(ka, 32); ka += __shfl_down(ka, 16); ka += __shfl_down(ka, 8);
    ka += __shfl_down(ka, 4);  ka += __shfl_down(ka, 2);  ka += __shfl_down(ka, 1);
    if (lane == 0) red[wid] = ka;
    __syncthreads();
    if (threadIdx.x == 0) P.klics[blk] = red[0] + red[1] + red[2] + red[3];
  } else {
    const int lane = threadIdx.x & 63, wid = threadIdx.x >> 6;
    const int cl = lane & 15, rq = (lane >> 4) << 2;
    const int gw = (blk - 32) * 4 + wid;
    const size_t r0 = (size_t)gw << 4;
    const float* Fs = P.out + FOUT;
    short8 F0 = ldfrag_f32(Fs + r0 * 64, 64);
    short8 F1 = ldfrag_f32(Fs + r0 * 64 + 32, 64);
    #pragma unroll 1
    for (int ct = 0; ct < 16; ++ct) {
      const int d0 = ct << 4;
      const u16* W = P.wrbf + (size_t)d0 * 64;
      f32x4 a = {0,0,0,0};
      a = MFMA(ldfrag(W, 64), F0, a);
      a = MFMA(ldfrag(W + 32, 64), F1, a);
      f32x4 rb = *(const f32x4*)(P.b_r + d0 + rq);
      f32x4 o;
      o[0] = __expf(a[0] + rb[0]); o[1] = __expf(a[1] + rb[1]);
      o[2] = __expf(a[2] + rb[2]); o[3] = __expf(a[3] + rb[3]);
      *(f32x4*)(P.out + (r0 + cl) * 256 + d0 + rq) = o;
    }
  }
}

__global__ void k_final(Params P) {
  if (threadIdx.x == 0) {
    float s = 0.f, s2 = 0.f;
    for (int i = 0; i < 16; ++i) s += P.klacc[i];
    for (int i = 0; i < 32; ++i) s2 += P.klics[i];
    P.out[RATES_N]     = s2 * (0.5f / 256.f);
    P.out[RATES_N + 1] = s  * (0.5f / (256.f * 512.f));
  }
}

// ---------------------------------------------------------------- launch
extern "C" void kernel_launch(void* const* d_in, const int* in_sizes, int n_in,
                              void* d_out, int out_size, void* d_ws, size_t ws_size,
                              hipStream_t stream) {
  (void)in_sizes; (void)n_in; (void)out_size;
  Params P;
  const float* const* in = (const float* const*)d_in;
  P.x = in[0];      P.eps = in[1];
  P.Wih_ef = in[2]; P.Whh_ef = in[3]; P.bih_ef = in[4]; P.bhh_ef = in[5];
  P.Wih_eb = in[6]; P.Whh_eb = in[7]; P.bih_eb = in[8]; P.bhh_eb = in[9];
  P.W_mu0 = in[10]; P.b_mu0 = in[11]; P.W_lv0 = in[12]; P.b_lv0 = in[13];
  P.Wih_c = in[14]; P.Whh_c = in[15]; P.bih_c = in[16]; P.bhh_c = in[17];
  P.W_cmu = in[18]; P.b_cmu = in[19]; P.W_clv = in[20]; P.b_clv = in[21];
  P.Wih_g = in[22]; P.Whh_g = in[23]; P.bih_g = in[24]; P.bhh_g = in[25];
  P.W_f = in[26];   P.b_f = in[27];   P.W_r = in[28];   P.b_r = in[29];

  char* w = (char*)d_ws;
  size_t off = 0;
  auto take = [&](size_t bytes) -> char* {
    char* r = w + off;
    off = (off + bytes + 255) & ~(size_t)255;
    return r;
  };
  P.Xf8     = (u8*)take(33554432ull);
  P.ebf     = (u16*)take(16777216ull * 2);
  P.wihcbf  = (u16*)take(196608ull * 2);
  P.wihefbf = (u16*)take(196608ull * 2);
  P.wihebbf = (u16*)take(196608ull * 2);
  P.bfc     = (float*)take(768ull * 4);
  P.bfe     = (float*)take(1536ull * 4);
  P.wihef8  = (u8*)take(196608ull);
  P.whhef8  = (u8*)take(196608ull);
  P.wiheb8  = (u8*)take(196608ull);
  P.whheb8  = (u8*)take(196608ull);
  P.whhc8   = (u8*)take(196608ull);
  P.whhg8   = (u8*)take(196608ull);
  P.wcomb8  = (u8*)take(196608ull);
  P.wihg8   = (u8*)take(49152ull);
  P.wf8     = (u8*)take(16384ull);
  P.wcmu8   = (u8*)take(16384ull);
  P.wclv8   = (u8*)take(16384ull);
  P.wrbf    = (u16*)take(16384ull * 2);
  P.foldc   = (float*)take(768ull * 4);
  P.cbn     = (float*)take(256ull * 4);
  P.ebn     = (float*)take(512ull * 4);
  P.gb      = (float*)take(1024ull * 4);
  P.hdb     = (float*)take(128ull * 4);
  P.fb2     = (float*)take(64ull * 4);
  P.eb      = (float*)take(2048ull * 4);
  P.henc    = (float*)take(131072ull * 4);
  P.klacc   = (float*)take(64ull * 4);
  P.klics   = (float*)take(64ull * 4);
  size_t gxe_off = (off + 255) & ~(size_t)255;
  P.useGxe = (gxe_off + 2 * GXE_D <= ws_size) ? 1 : 0;
  P.Gxe = P.useGxe ? (u8*)(w + gxe_off) : (u8*)w;
  P.Gxc = (u8*)d_out;
  P.out = (float*)d_out;

  hipLaunchKernelGGL(k_init,  dim3(2048), dim3(256), 0, stream, P);
  hipLaunchKernelGGL(k_gx,    dim3(6144), dim3(512), 131072, stream, P);
  hipLaunchKernelGGL(k_main,  dim3(48),   dim3(512), 147456, stream, P);
  hipLaunchKernelGGL(k_post,  dim3(2080), dim3(256), 0, stream, P);
  hipLaunchKernelGGL(k_final, dim3(1),    dim3(64),  0, stream, P);
}

// Round 16
// 4591.840 us; speedup vs baseline: 1.2773x; 1.2773x over previous
//
#include <hip/hip_runtime.h>

typedef unsigned char u8;
typedef unsigned short u16;
typedef unsigned int u32;
typedef unsigned long long u64;
typedef short short8 __attribute__((ext_vector_type(8)));
typedef __bf16 bf16x8 __attribute__((ext_vector_type(8)));
typedef float f32x4 __attribute__((ext_vector_type(4)));
typedef float f32x2 __attribute__((ext_vector_type(2)));
typedef long longx2 __attribute__((ext_vector_type(2)));

#define DEV static __device__ __forceinline__

// ---------------------------------------------------------------- params
struct Params {
  const float *x, *eps;
  const float *Wih_ef, *Whh_ef, *bih_ef, *bhh_ef;
  const float *Wih_eb, *Whh_eb, *bih_eb, *bhh_eb;
  const float *W_mu0, *b_mu0, *W_lv0, *b_lv0;
  const float *Wih_c, *Whh_c, *bih_c, *bhh_c;
  const float *W_cmu, *b_cmu, *W_clv, *b_clv;
  const float *Wih_g, *Whh_g, *bih_g, *bhh_g;
  const float *W_f, *b_f, *W_r, *b_r;
  // workspace (weights FRAGMENT-LINEAR swizzled)
  u8  *Xf8;                 // [T][B][256] fp8 (fallback enc path only)
  u16 *ebf;                 // eps swizzled
  u16 *wihcbf, *wihefbf, *wihebbf;   // [768][256] bf16 (k_gx A matrices)
  float *bfc;               // [768] ctrl fused bias
  float *bfe;               // [2][768] enc fused bias
  u8 *wihef8, *whhef8, *wiheb8, *whheb8;    // enc fp8, swizzled K=256
  u8 *whhc8, *whhg8;                        // cg fp8, swizzled K=256
  u8 *wihcf8, *wihg8;                       // swizzled K=64
  u8 *wf8, *wcmu8, *wclv8;                  // swizzled (R=64)
  u16 *wrbf;                                // [256][64] bf16 (k_post)
  float *cbn;               // [256] bhh_c n-gate
  float *ebn;               // [2][256] bhh_e n-gate
  float *gb;                // [4][256] gen biases
  float *hdb;               // [128]
  float *fb2;               // [64]
  float *eb;                // [2][4][256] enc biases (fallback)
  float *henc;              // [2*256][256]
  float *klacc;             // [16]
  float *klics;             // [32]
  u8 *Gxc;                  // parked in rates region
  u8 *Gxe;                  // [dir] (ws, optional)
  int useGxe;
  float *out;
};

constexpr size_t RATES_N = 33554432ull;
constexpr size_t FOUT    = RATES_N + 2ull;
constexpr size_t GXE_D   = 100663296ull;

// ---------------------------------------------------------------- scalar helpers
DEV u16 f2bf(float x) {
  unsigned u = __builtin_bit_cast(unsigned, x);
  u = (u + 0x7FFFu + ((u >> 16) & 1u)) >> 16;
  return (u16)u;
}
DEV float bf2f(u32 s) { return __builtin_bit_cast(float, s << 16); }
DEV unsigned f2e4m3(float x) {
  unsigned u = __builtin_bit_cast(unsigned, x);
  unsigned s = (u >> 24) & 0x80u;
  float ax = __builtin_bit_cast(float, u & 0x7FFFFFFFu);
  if (ax > 448.f) return s | 0x7E;
  if (ax < 0.0009765625f) return s;
  if (ax < 0.015625f) {
    int m = (int)rintf(ax * 512.f);
    if (m >= 8) return s | 0x08;
    return s | (unsigned)m;
  }
  unsigned au = __builtin_bit_cast(unsigned, ax);
  int E = (int)(au >> 23) - 127;
  unsigned m = au & 0x7FFFFFu;
  unsigned r = (m + 0x7FFFFu + ((m >> 20) & 1u)) >> 20;
  if (r >= 8) { r = 0; ++E; if (E > 8) return s | 0x7E; }
  return s | ((unsigned)(E + 7) << 3) | r;
}
DEV float e4m3tof(unsigned b) {
  unsigned s = (b & 0x80u) << 24;
  unsigned e = (b >> 3) & 15u, m = b & 7u;
  float v;
  if (e) v = __builtin_bit_cast(float, ((e + 120u) << 23) | (m << 20));
  else   v = (float)m * 0.001953125f;
  return __builtin_bit_cast(float, __builtin_bit_cast(unsigned, v) | s);
}
template <bool HI>
DEV unsigned pk2fp8(float a, float b, unsigned old) {
#if __has_builtin(__builtin_amdgcn_cvt_pk_fp8_f32)
  return (unsigned)__builtin_amdgcn_cvt_pk_fp8_f32(a, b, (int)old, HI);
#else
  unsigned p = f2e4m3(a) | (f2e4m3(b) << 8);
  return HI ? ((old & 0xFFFFu) | (p << 16)) : ((old & 0xFFFF0000u) | p);
#endif
}
template <bool HI>
DEV f32x2 pkf32(unsigned w) {
#if __has_builtin(__builtin_amdgcn_cvt_pk_f32_fp8)
  return __builtin_amdgcn_cvt_pk_f32_fp8((int)w, HI);
#else
  unsigned h = HI ? (w >> 16) : w;
  f32x2 r; r[0] = e4m3tof(h & 255u); r[1] = e4m3tof((h >> 8) & 255u); return r;
#endif
}
DEV float sigm(float x) { return 1.f / (1.f + __expf(-x)); }
DEV float ftanh(float x) { float t = __expf(2.f * x); return 1.f - 2.f / (t + 1.f); }
DEV float gru_h(float pr, float pz, float pin, float phn, float hp) {
  float r = sigm(pr), z = sigm(pz);
  float n = ftanh(pin + r * phn);
  return (1.f - z) * n + z * hp;
}
DEV u64 pack8f8(const float* s) {
  u64 p = 0;
  #pragma unroll
  for (int e = 0; e < 8; ++e) p |= (u64)f2e4m3(s[e]) << (8 * e);
  return p;
}

// ---------------------------------------------------------------- MFMA helpers
DEV f32x4 MFMA(short8 a, short8 b, f32x4 c) {
  return __builtin_amdgcn_mfma_f32_16x16x32_bf16(
      __builtin_bit_cast(bf16x8, a), __builtin_bit_cast(bf16x8, b), c, 0, 0, 0);
}
DEV f32x4 mfma8(long a, long b, f32x4 c) {
  return __builtin_amdgcn_mfma_f32_16x16x32_fp8_fp8(a, b, c, 0, 0, 0);
}
DEV short8 ldfrag(const u16* p0, int stride) {
  const int l = threadIdx.x & 63;
  const u16* p = p0 + (size_t)(l & 15) * stride + ((l >> 4) << 3);
  return *reinterpret_cast<const short8*>(p);
}
DEV short8 ldfrag_f32(const float* p0, int stride) {
  const int l = threadIdx.x & 63;
  const float* p = p0 + (size_t)(l & 15) * stride + ((l >> 4) << 3);
  f32x4 a = *reinterpret_cast<const f32x4*>(p);
  f32x4 b = *reinterpret_cast<const f32x4*>(p + 4);
  short8 r;
  r[0]=(short)f2bf(a[0]); r[1]=(short)f2bf(a[1]); r[2]=(short)f2bf(a[2]); r[3]=(short)f2bf(a[3]);
  r[4]=(short)f2bf(b[0]); r[5]=(short)f2bf(b[1]); r[6]=(short)f2bf(b[2]); r[7]=(short)f2bf(b[3]);
  return r;
}
// fragment-linear readers: global and LDS share the same offset math
DEV longx2 ldws2(const u8* w, int tile, int p) {
  return *(const longx2*)(w + ((size_t)tile << 12) + (p << 10) + ((threadIdx.x & 63) << 4));
}
DEV longx2 ldws64x(const u8* w, int tile) {
  return *(const longx2*)(w + ((size_t)tile << 10) + ((threadIdx.x & 63) << 4));
}
// ---------- fragment-native LDS state layout ----------
DEV int fragoff(int row, int jb) { return jb * 128 + ((row ^ (jb & 15)) << 3); }
DEV long ldsF(const u8* m, int kk) {
  int l = threadIdx.x & 63;
  int jb = kk * 4 + (l >> 4);
  return *(const long*)(m + fragoff(l & 15, jb));
}
DEV void stF(u8* m, int row, int col, unsigned v) {
  *(unsigned*)(m + fragoff(row, col >> 3) + (col & 7)) = v;
}
// bf16 helpers for k_gx
DEV short8 ldsB16(const u8* m, int r0, int kk) {
  int l = threadIdx.x & 63;
  int row = r0 + (l & 15);
  int off = row * 512 + kk * 64 + ((l >> 4) << 4);
  off ^= (row & 7) << 4;
  return *(const short8*)(m + off);
}
DEV void stage16(u8* dst, const u8* src, int nbytes) {
  for (int i = threadIdx.x * 16; i < nbytes; i += blockDim.x * 16) {
    int row = i >> 9;
    int off = i ^ ((row & 7) << 4);
    *(f32x4*)(dst + off) = *(const f32x4*)(src + i);
  }
}
DEV void stageLin(u8* dst, const u8* src, int nbytes) {
  for (int i = threadIdx.x * 16; i < nbytes; i += 512 * 16)
    *(f32x4*)(dst + i) = *(const f32x4*)(src + i);
}

// ---------------------------------------------------------------- k_init
__global__ __launch_bounds__(256) void k_init(Params P) {
  const size_t g  = (size_t)blockIdx.x * 256 + threadIdx.x;
  const size_t gs = (size_t)gridDim.x * 256;
  if (!P.useGxe) {
    for (size_t i = g; i < 4194304ull; i += gs) {
      size_t flat = i << 3;
      int b = (int)(flat >> 17);
      int rem = (int)(flat & 131071);
      int t = rem >> 8, d = rem & 255;
      *(u64*)(P.Xf8 + (((size_t)t * 256 + b) << 8) + d) = pack8f8(P.x + flat);
    }
  }
  for (size_t o = g; o < 1048576ull; o += gs) {
    int l = (int)(o & 63), k2 = (int)((o >> 6) & 1);
    int bt = (int)((o >> 7) & 15), t = (int)(o >> 11);
    int row = bt * 16 + (l & 15), col = k2 * 32 + ((l >> 4) << 3);
    const float* s = P.eps + ((size_t)t * 256 + row) * 64 + col;
    f32x4 v0 = *(const f32x4*)s, v1 = *(const f32x4*)(s + 4);
    short8 ob;
    ob[0]=(short)f2bf(v0[0]); ob[1]=(short)f2bf(v0[1]); ob[2]=(short)f2bf(v0[2]); ob[3]=(short)f2bf(v0[3]);
    ob[4]=(short)f2bf(v1[0]); ob[5]=(short)f2bf(v1[1]); ob[6]=(short)f2bf(v1[2]); ob[7]=(short)f2bf(v1[3]);
    *(short8*)((u8*)P.ebf + o * 16) = ob;
  }
  const int gi = (int)g, gsi = (int)gs;
  for (int i = gi; i < 24576; i += gsi) {
    int l = i & 63, kk = (i >> 6) & 7, tile = i >> 9;
    int row = tile * 16 + (l & 15), col = kk * 32 + ((l >> 4) << 3);
    size_t so = (size_t)row * 256 + col;
    size_t db = ((size_t)tile << 12) + ((kk >> 1) << 10) + (l << 4) + ((kk & 1) << 3);
    *(u64*)(P.whhc8  + db) = pack8f8(P.Whh_c  + so);
    *(u64*)(P.whhg8  + db) = pack8f8(P.Whh_g  + so);
    *(u64*)(P.wihef8 + db) = pack8f8(P.Wih_ef + so);
    *(u64*)(P.whhef8 + db) = pack8f8(P.Whh_ef + so);
    *(u64*)(P.wiheb8 + db) = pack8f8(P.Wih_eb + so);
    *(u64*)(P.whheb8 + db) = pack8f8(P.Whh_eb + so);
  }
  for (int i = gi; i < 2048; i += gsi) {
    int l = i & 63, kk = (i >> 6) & 7, tile = i >> 9;
    int row = tile * 16 + (l & 15), col = kk * 32 + ((l >> 4) << 3);
    size_t so = (size_t)row * 256 + col;
    size_t db = ((size_t)tile << 12) + ((kk >> 1) << 10) + (l << 4) + ((kk & 1) << 3);
    *(u64*)(P.wf8   + db) = pack8f8(P.W_f   + so);
    *(u64*)(P.wcmu8 + db) = pack8f8(P.W_cmu + so);
    *(u64*)(P.wclv8 + db) = pack8f8(P.W_clv + so);
  }
  for (int i = gi; i < 6144; i += gsi) {
    int l = i & 63, k2 = (i >> 6) & 1, tile = i >> 7;
    int row = tile * 16 + (l & 15), col = k2 * 32 + ((l >> 4) << 3);
    size_t db = ((size_t)tile << 10) + (l << 4) + (k2 << 3);
    *(u64*)(P.wihcf8 + db) = pack8f8(P.Wih_c + (size_t)row * 320 + 256 + col);
    *(u64*)(P.wihg8  + db) = pack8f8(P.Wih_g + (size_t)row * 64 + col);
  }
  for (int i = gi; i < 196608; i += gsi) {
    int r = i >> 8, c = i & 255;
    P.wihcbf[i]  = f2bf(P.Wih_c[r * 320 + c]);
    P.wihefbf[i] = f2bf(P.Wih_ef[i]);
    P.wihebbf[i] = f2bf(P.Wih_eb[i]);
  }
  for (int i = gi; i < 16384; i += gsi) P.wrbf[i] = f2bf(P.W_r[i]);
  for (int i = gi; i < 768; i += gsi) {
    P.bfc[i] = P.bih_c[i] + (i < 512 ? P.bhh_c[i] : 0.f);
    P.bfe[i]       = P.bih_ef[i] + (i < 512 ? P.bhh_ef[i] : 0.f);
    P.bfe[768 + i] = P.bih_eb[i] + (i < 512 ? P.bhh_eb[i] : 0.f);
  }
  for (int i = gi; i < 256; i += gsi) {
    P.cbn[i] = P.bhh_c[512 + i];
    P.ebn[i]       = P.bhh_ef[512 + i];
    P.ebn[256 + i] = P.bhh_eb[512 + i];
    P.gb[i]        = P.bih_g[i] + P.bhh_g[i];
    P.gb[256 + i]  = P.bih_g[256 + i] + P.bhh_g[256 + i];
    P.gb[512 + i]  = P.bih_g[512 + i];
    P.gb[768 + i]  = P.bhh_g[512 + i];
    P.eb[i]        = P.bih_ef[i] + P.bhh_ef[i];
    P.eb[256 + i]  = P.bih_ef[256 + i] + P.bhh_ef[256 + i];
    P.eb[512 + i]  = P.bih_ef[512 + i];
    P.eb[768 + i]  = P.bhh_ef[512 + i];
    P.eb[1024 + i] = P.bih_eb[i] + P.bhh_eb[i];
    P.eb[1280 + i] = P.bih_eb[256 + i] + P.bhh_eb[256 + i];
    P.eb[1536 + i] = P.bih_eb[512 + i];
    P.eb[1792 + i] = P.bhh_eb[512 + i];
  }
  for (int i = gi; i < 128; i += gsi) P.hdb[i] = (i < 64) ? P.b_cmu[i] : P.b_clv[i - 64];
  for (int i = gi; i < 64; i += gsi)  P.fb2[i] = P.b_f[i];
}

// ---------------------------------------------------------------- k_gx : one block does all (up to 3) matrices; x staged once
__global__ __launch_bounds__(512, 2) void k_gx(Params P) {
  extern __shared__ char smem[];
  u8* sA = (u8*)smem;
  u8* sB = sA + 65536;
  const int nc = blockIdx.x % 6;
  const int tb = blockIdx.x / 6;
  const int t = tb >> 1, bh = tb & 1;
  for (int i = threadIdx.x * 8; i < 32768; i += 512 * 8) {
    int r = i >> 8, c = i & 255;
    const float* s = P.x + ((size_t)(bh * 128 + r) * 512 + t) * 256 + c;
    f32x4 v0 = *(const f32x4*)s, v1 = *(const f32x4*)(s + 4);
    short8 o;
    o[0]=(short)f2bf(v0[0]); o[1]=(short)f2bf(v0[1]); o[2]=(short)f2bf(v0[2]); o[3]=(short)f2bf(v0[3]);
    o[4]=(short)f2bf(v1[0]); o[5]=(short)f2bf(v1[1]); o[6]=(short)f2bf(v1[2]); o[7]=(short)f2bf(v1[3]);
    int off = (r * 512 + c * 2) ^ ((r & 7) << 4);
    *(short8*)(sB + off) = o;
  }
  const int lane = threadIdx.x & 63, wid = threadIdx.x >> 6;
  const int rq = (lane >> 4) << 2;
  const int nglob = nc * 128 + wid * 16;
  const int nmm = P.useGxe ? 3 : 1;
  #pragma unroll 1
  for (int mm = 0; mm < nmm; ++mm) {
    const u16* Abf = (mm == 0) ? P.wihcbf : ((mm == 1) ? P.wihefbf : P.wihebbf);
    const float* bias = (mm == 0) ? P.bfc : (P.bfe + (mm - 1) * 768);
    u8* dst = (mm == 0) ? P.Gxc : (P.Gxe + (size_t)(mm - 1) * GXE_D);
    stage16(sA, (const u8*)(Abf + (size_t)nc * 128 * 256), 65536);
    __syncthreads();
    short8 Af[8];
    #pragma unroll
    for (int kk = 0; kk < 8; ++kk) Af[kk] = ldsB16(sA, wid * 16, kk);
    float bq[4];
    #pragma unroll
    for (int q = 0; q < 4; ++q) bq[q] = bias[nglob + rq + q];
    #pragma unroll 1
    for (int bt = 0; bt < 8; ++bt) {
      f32x4 acc = {0.f, 0.f, 0.f, 0.f};
      #pragma unroll
      for (int kk = 0; kk < 8; ++kk)
        acc = MFMA(Af[kk], ldsB16(sB, bt * 16, kk), acc);
      float v0 = acc[0] + bq[0], v1 = acc[1] + bq[1], v2 = acc[2] + bq[2], v3 = acc[3] + bq[3];
      unsigned pw = pk2fp8<false>(v0, v1, 0u); pw = pk2fp8<true>(v2, v3, pw);
      *(u32*)(dst + (((size_t)(t * 16 + bh * 8 + bt) * 48 + (nglob >> 4)) << 8) + (lane << 2)) = pw;
    }
    __syncthreads();
  }
}

// ---------------------------------------------------------------- k_main
DEV void cg_role(const Params& P, int blk, char* smem) {
  u8* sWcf = (u8*)smem;                 // 49152
  u8* sWg  = sWcf + 49152;              // 49152
  u8* sWhd = sWg + 49152;               // 32768
  u8* hc8  = sWhd + 32768;              // 2*4096
  u8* hg8  = hc8 + 8192;                // 2*4096
  u8* f8b  = hg8 + 8192;                // 2*1024
  float* sml  = (float*)(f8b + 2048);   // 8448
  float* sred = sml + 16 * 132;         // 64

  const int lane = threadIdx.x & 63, wid = threadIdx.x >> 6;  // 8 waves
  const int cl = lane & 15, rq = (lane >> 4) << 2;
  const int b0 = blk << 4, j0 = wid << 5, jt = wid << 1;
  const int sel = wid >> 2, l0 = (wid & 3) << 4;

  stageLin(sWcf, P.wihcf8, 49152);
  stageLin(sWg,  P.wihg8,  49152);
  stageLin(sWhd, P.wcmu8, 16384);
  stageLin(sWhd + 16384, P.wclv8, 16384);
  for (int i = threadIdx.x * 4; i < 18432; i += 512 * 4) *(int*)(hc8 + i) = 0;

  f32x4 bnv[2], brv[2], bzv[2], biv[2], bhv2[2];
  #pragma unroll
  for (int c2 = 0; c2 < 2; ++c2) {
    int j = j0 + c2 * 16 + rq;
    bnv[c2]  = *(const f32x4*)(P.cbn + j);
    brv[c2]  = *(const f32x4*)(P.gb + j);
    bzv[c2]  = *(const f32x4*)(P.gb + 256 + j);
    biv[c2]  = *(const f32x4*)(P.gb + 512 + j);
    bhv2[c2] = *(const f32x4*)(P.gb + 768 + j);
  }
  f32x4 hbv = *(const f32x4*)(P.hdb + sel * 64 + l0 + rq);
  f32x4 fbv = {0, 0, 0, 0};
  if (wid < 4) fbv = *(const f32x4*)(P.fb2 + (wid << 4) + rq);

  f32x4 hcM[2] = {{0,0,0,0},{0,0,0,0}};
  f32x4 hgM[2] = {{0,0,0,0},{0,0,0,0}};
  float klv = 0.f;
  // pre-loop prefetch of whhc (c2=0) -- consumed by first P1
  longx2 pc0[4], pc1[4], pc2[4];
  #pragma unroll
  for (int p = 0; p < 4; ++p) {
    pc0[p] = ldws2(P.whhc8,      jt, p);
    pc1[p] = ldws2(P.whhc8, 16 + jt, p);
    pc2[p] = ldws2(P.whhc8, 32 + jt, p);
  }
  __syncthreads();

  #pragma unroll 1
  for (int t = 0; t < 512; ++t) {
    const int cur = t & 1, prv = cur ^ 1;
    u8 *hcP = hc8 + prv * 4096, *hcC = hc8 + cur * 4096;
    u8 *hgP = hg8 + prv * 4096, *hgC = hg8 + cur * 4096;
    // early coalesced Gxc + eps
    u32 gx[6];
    { const u8* gp = P.Gxc + (((size_t)(t * 16 + blk) * 48) << 8) + (lane << 2);
      #pragma unroll
      for (int c2 = 0; c2 < 2; ++c2)
        #pragma unroll
        for (int g3 = 0; g3 < 3; ++g3)
          gx[c2 * 3 + g3] = *(const u32*)(gp + ((g3 * 16 + jt + c2) << 8));
    }
    short8 ee0 = *(const short8*)((const u8*)P.ebf + (((size_t)(t * 16 + blk) * 2 + 0) << 10) + lane * 16);
    short8 ee1 = *(const short8*)((const u8*)P.ebf + (((size_t)(t * 16 + blk) * 2 + 1) << 10) + lane * 16);
    // ---- P1: controller GRU (c2=0 from prefetch; c2=1 streamed) ----
    long hf[8];
    #pragma unroll
    for (int kk = 0; kk < 8; ++kk) hf[kk] = ldsF(hcP, kk);
    long ff0, ff1;
    { int l = threadIdx.x & 63;
      int jb0 = 0 * 4 + (l >> 4), jb1 = 1 * 4 + (l >> 4);
      ff0 = *(const long*)(f8b + prv * 1024 + fragoff(l & 15, jb0));
      ff1 = *(const long*)(f8b + prv * 1024 + fragoff(l & 15, jb1));
    }
    #pragma unroll
    for (int c2 = 0; c2 < 2; ++c2) {
      longx2 w0[4], w1[4], w2[4];
      if (c2 == 0) {
        #pragma unroll
        for (int p = 0; p < 4; ++p) { w0[p] = pc0[p]; w1[p] = pc1[p]; w2[p] = pc2[p]; }
      } else {
        #pragma unroll
        for (int p = 0; p < 4; ++p) {
          w0[p] = ldws2(P.whhc8,      jt + 1, p);
          w1[p] = ldws2(P.whhc8, 16 + jt + 1, p);
          w2[p] = ldws2(P.whhc8, 32 + jt + 1, p);
        }
      }
      longx2 cf0 = ldws64x(sWcf,      jt + c2);
      longx2 cf1 = ldws64x(sWcf, 16 + jt + c2);
      longx2 cf2 = ldws64x(sWcf, 32 + jt + c2);
      f32x4 ar = {0,0,0,0}, az = {0,0,0,0}, ai = {0,0,0,0}, ah = {0,0,0,0};
      #pragma unroll
      for (int p = 0; p < 4; ++p) {
        ar = mfma8(w0[p].x, hf[2*p], ar);  ar = mfma8(w0[p].y, hf[2*p+1], ar);
        az = mfma8(w1[p].x, hf[2*p], az);  az = mfma8(w1[p].y, hf[2*p+1], az);
        ah = mfma8(w2[p].x, hf[2*p], ah);  ah = mfma8(w2[p].y, hf[2*p+1], ah);
      }
      ar = mfma8(cf0.x, ff0, ar); ar = mfma8(cf0.y, ff1, ar);
      az = mfma8(cf1.x, ff0, az); az = mfma8(cf1.y, ff1, az);
      ai = mfma8(cf2.x, ff0, ai); ai = mfma8(cf2.y, ff1, ai);
      f32x2 rlo = pkf32<false>(gx[c2*3+0]), rhi = pkf32<true>(gx[c2*3+0]);
      f32x2 zlo = pkf32<false>(gx[c2*3+1]), zhi = pkf32<true>(gx[c2*3+1]);
      f32x2 nlo = pkf32<false>(gx[c2*3+2]), nhi = pkf32<true>(gx[c2*3+2]);
      f32x4 bn = bnv[c2];
      float h0 = gru_h(ar[0]+rlo[0], az[0]+zlo[0], ai[0]+nlo[0], ah[0]+bn[0], hcM[c2][0]);
      float h1 = gru_h(ar[1]+rlo[1], az[1]+zlo[1], ai[1]+nlo[1], ah[1]+bn[1], hcM[c2][1]);
      float h2 = gru_h(ar[2]+rhi[0], az[2]+zhi[0], ai[2]+nhi[0], ah[2]+bn[2], hcM[c2][2]);
      float h3 = gru_h(ar[3]+rhi[1], az[3]+zhi[1], ai[3]+nhi[1], ah[3]+bn[3], hcM[c2][3]);
      hcM[c2][0] = h0; hcM[c2][1] = h1; hcM[c2][2] = h2; hcM[c2][3] = h3;
      unsigned pw = pk2fp8<false>(h0, h1, 0u); pw = pk2fp8<true>(h2, h3, pw);
      stF(hcC, cl, j0 + c2 * 16 + rq, pw);
    }
    // cross-barrier prefetch of P3's whhg (c2=0)
    longx2 pg0[4], pg1[4], pg2[4];
    #pragma unroll
    for (int p = 0; p < 4; ++p) {
      pg0[p] = ldws2(P.whhg8,      jt, p);
      pg1[p] = ldws2(P.whhg8, 16 + jt, p);
      pg2[p] = ldws2(P.whhg8, 32 + jt, p);
    }
    __syncthreads();                                    // B1
    // ---- P2: heads -> sml ----
    { long hcv[8];
      #pragma unroll
      for (int kk = 0; kk < 8; ++kk) hcv[kk] = ldsF(hcC, kk);
      f32x4 am = {0,0,0,0};
      #pragma unroll
      for (int p = 0; p < 4; ++p) {
        longx2 wp = ldws2(sWhd + sel * 16384, wid & 3, p);
        am = mfma8(wp.x, hcv[2*p], am);
        am = mfma8(wp.y, hcv[2*p+1], am);
      }
      am += hbv;
      *(f32x4*)(sml + cl * 132 + sel * 64 + l0 + rq) = am;
    }
    __syncthreads();                                    // B2
    // ---- P3: u + generator GRU ----
    long U[2];
    { const float* ml = sml + cl * 132;
      const int kh = (lane >> 4) << 3;
      #pragma unroll
      for (int k2 = 0; k2 < 2; ++k2) {
        f32x4 mu0 = *(const f32x4*)(ml + k2 * 32 + kh);
        f32x4 mu1 = *(const f32x4*)(ml + k2 * 32 + kh + 4);
        f32x4 lv0 = *(const f32x4*)(ml + 64 + k2 * 32 + kh);
        f32x4 lv1 = *(const f32x4*)(ml + 64 + k2 * 32 + kh + 4);
        short8 ev = k2 ? ee1 : ee0;
        float uu[8];
        #pragma unroll
        for (int e = 0; e < 4; ++e) {
          float epv = bf2f((u32)(u16)ev[e]);
          uu[e] = mu0[e] + epv * __expf(0.5f * lv0[e]);
        }
        #pragma unroll
        for (int e = 0; e < 4; ++e) {
          float epv = bf2f((u32)(u16)ev[4 + e]);
          uu[4 + e] = mu1[e] + epv * __expf(0.5f * lv1[e]);
        }
        unsigned pa = pk2fp8<false>(uu[0], uu[1], 0u); pa = pk2fp8<true>(uu[2], uu[3], pa);
        unsigned pb = pk2fp8<false>(uu[4], uu[5], 0u); pb = pk2fp8<true>(uu[6], uu[7], pb);
        U[k2] = (long)(((u64)pb << 32) | (u64)pa);
      }
    }
    long hg[8];
    #pragma unroll
    for (int kk = 0; kk < 8; ++kk) hg[kk] = ldsF(hgP, kk);
    #pragma unroll
    for (int c2 = 0; c2 < 2; ++c2) {
      longx2 g0[4], g1[4], g2[4];
      if (c2 == 0) {
        #pragma unroll
        for (int p = 0; p < 4; ++p) { g0[p] = pg0[p]; g1[p] = pg1[p]; g2[p] = pg2[p]; }
      } else {
        #pragma unroll
        for (int p = 0; p < 4; ++p) {
          g0[p] = ldws2(P.whhg8,      jt + 1, p);
          g1[p] = ldws2(P.whhg8, 16 + jt + 1, p);
          g2[p] = ldws2(P.whhg8, 32 + jt + 1, p);
        }
      }
      longx2 u0 = ldws64x(sWg,      jt + c2);
      longx2 u1 = ldws64x(sWg, 16 + jt + c2);
      longx2 u2 = ldws64x(sWg, 32 + jt + c2);
      f32x4 gr = {0,0,0,0}, gz = {0,0,0,0}, gi = {0,0,0,0}, gh = {0,0,0,0};
      #pragma unroll
      for (int p = 0; p < 4; ++p) {
        gr = mfma8(g0[p].x, hg[2*p], gr);  gr = mfma8(g0[p].y, hg[2*p+1], gr);
        gz = mfma8(g1[p].x, hg[2*p], gz);  gz = mfma8(g1[p].y, hg[2*p+1], gz);
        gh = mfma8(g2[p].x, hg[2*p], gh);  gh = mfma8(g2[p].y, hg[2*p+1], gh);
      }
      gr = mfma8(u0.x, U[0], gr); gr = mfma8(u0.y, U[1], gr);
      gz = mfma8(u1.x, U[0], gz); gz = mfma8(u1.y, U[1], gz);
      gi = mfma8(u2.x, U[0], gi); gi = mfma8(u2.y, U[1], gi);
      float h0 = gru_h(gr[0]+brv[c2][0], gz[0]+bzv[c2][0], gi[0]+biv[c2][0], gh[0]+bhv2[c2][0], hgM[c2][0]);
      float h1 = gru_h(gr[1]+brv[c2][1], gz[1]+bzv[c2][1], gi[1]+biv[c2][1], gh[1]+bhv2[c2][1], hgM[c2][1]);
      float h2 = gru_h(gr[2]+brv[c2][2], gz[2]+bzv[c2][2], gi[2]+biv[c2][2], gh[2]+bhv2[c2][2], hgM[c2][2]);
      float h3 = gru_h(gr[3]+brv[c2][3], gz[3]+bzv[c2][3], gi[3]+biv[c2][3], gh[3]+bhv2[c2][3], hgM[c2][3]);
      hgM[c2][0] = h0; hgM[c2][1] = h1; hgM[c2][2] = h2; hgM[c2][3] = h3;
      unsigned pw = pk2fp8<false>(h0, h1, 0u); pw = pk2fp8<true>(h2, h3, pw);
      stF(hgC, cl, j0 + c2 * 16 + rq, pw);
    }
    __syncthreads();                                    // B3
    // ---- P4: prefetch next whhc (c2=0) + factors + KL ----
    #pragma unroll
    for (int p = 0; p < 4; ++p) {
      pc0[p] = ldws2(P.whhc8,      jt, p);
      pc1[p] = ldws2(P.whhc8, 16 + jt, p);
      pc2[p] = ldws2(P.whhc8, 32 + jt, p);
    }
    if (wid < 4) {
      long hgv[8];
      #pragma unroll
      for (int kk = 0; kk < 8; ++kk) hgv[kk] = ldsF(hgC, kk);
      f32x4 af = {0,0,0,0};
      #pragma unroll
      for (int p = 0; p < 4; ++p) {
        longx2 wp = ldws2(P.wf8, wid, p);
        af = mfma8(wp.x, hgv[2*p], af);
        af = mfma8(wp.y, hgv[2*p+1], af);
      }
      af += fbv;
      float* fo = P.out + FOUT + (size_t)(b0 + cl) * 32768 + (size_t)t * 64 + wid * 16 + rq;
      f32x2 lo = {af[0], af[1]}, hi2 = {af[2], af[3]};
      *(f32x2*)fo = lo;
      *(f32x2*)(fo + 2) = hi2;
      unsigned pw = pk2fp8<false>(af[0], af[1], 0u); pw = pk2fp8<true>(af[2], af[3], pw);
      stF(f8b + cur * 1024, cl, wid * 16 + rq, pw);
    } else {
      #pragma unroll
      for (int e = 0; e < 4; ++e) {
        int p = ((wid - 4) * 64 + lane) * 4 + e;
        int row = p >> 6, l = p & 63;
        float mu = sml[row * 132 + l], lv = sml[row * 132 + 64 + l];
        klv += __expf(lv) + mu * mu - 1.f - lv;
      }
    }
    __syncthreads();                                    // B4
  }
  if (wid >= 4) {
    float v = klv;
    v += __shfl_down(v, 32); v += __shfl_down(v, 16); v += __shfl_down(v, 8);
    v += __shfl_down(v, 4);  v += __shfl_down(v, 2);  v += __shfl_down(v, 1);
    if (lane == 0) sred[wid] = v;
  }
  __syncthreads();
  if (threadIdx.x == 0) P.klacc[blk] = sred[4] + sred[5] + sred[6] + sred[7];
}

// enc: Whh gates r,z LDS-persistent; gate n streamed.
template <bool GXE>
DEV void enc_role(const Params& P, int dir, int b0, char* smem) {
  u8* sWhh = (u8*)smem;                 // 131072
  u8* h8   = sWhh + 131072;             // 2*4096
  u8* sx   = h8 + 8192;                 // 2*4096 (fallback only)
  const int lane = threadIdx.x & 63, wid = threadIdx.x >> 6;
  const int cl = lane & 15, rq = (lane >> 4) << 2;
  const int j0 = wid << 5, jt = wid << 1;
  const int btile = b0 >> 4;
  const u8* wihG = dir ? P.wiheb8 : P.wihef8;
  const u8* whhG = dir ? P.whheb8 : P.whhef8;
  stageLin(sWhh, whhG, 131072);
  for (int i = threadIdx.x * 4; i < 8192; i += 512 * 4) *(int*)(h8 + i) = 0;
  f32x4 bnv[2], brv[2], bzv[2], biv[2], bhv2[2];
  #pragma unroll
  for (int c2 = 0; c2 < 2; ++c2) {
    int j = j0 + c2 * 16 + rq;
    if (GXE) {
      bnv[c2] = *(const f32x4*)(P.ebn + dir * 256 + j);
    } else {
      const float* ebt = P.eb + dir * 1024;
      brv[c2]  = *(const f32x4*)(ebt + j);
      bzv[c2]  = *(const f32x4*)(ebt + 256 + j);
      biv[c2]  = *(const f32x4*)(ebt + 512 + j);
      bhv2[c2] = *(const f32x4*)(ebt + 768 + j);
    }
  }
  f32x4 heM[2] = {{0,0,0,0},{0,0,0,0}};
  const int ssrc = threadIdx.x * 8;
  if (!GXE) {
    const int t0 = dir ? 511 : 0;
    *(u64*)(sx + fragoff(threadIdx.x >> 5, threadIdx.x & 31)) =
        *(const u64*)(P.Xf8 + (((size_t)t0 * 256 + b0) << 8) + ssrc);
  }
  __syncthreads();

  #pragma unroll 1
  for (int i = 0; i < 512; ++i) {
    const int cur = i & 1, prv = cur ^ 1;
    const int t = dir ? (511 - i) : i;
    u8 *hP = h8 + prv * 4096, *hC = h8 + cur * 4096;
    u32 gx[6];
    u64 xpre = 0;
    const u8* sxc = sx + cur * 4096;
    if (GXE) {
      const u8* gp = P.Gxe + (size_t)dir * GXE_D +
                     (((size_t)(t * 16 + btile) * 48) << 8) + (lane << 2);
      #pragma unroll
      for (int c2 = 0; c2 < 2; ++c2)
        #pragma unroll
        for (int g3 = 0; g3 < 3; ++g3)
          gx[c2 * 3 + g3] = *(const u32*)(gp + ((g3 * 16 + jt + c2) << 8));
    } else {
      if (i < 511) {
        int tn = dir ? (t - 1) : (t + 1);
        xpre = *(const u64*)(P.Xf8 + (((size_t)tn * 256 + b0) << 8) + ssrc);
      }
    }
    long hp[8];
    #pragma unroll
    for (int kk = 0; kk < 8; ++kk) hp[kk] = ldsF(hP, kk);
    #pragma unroll
    for (int c2 = 0; c2 < 2; ++c2) {
      longx2 Hr[4], Hz[4], Hn[4];
      #pragma unroll
      for (int p = 0; p < 4; ++p) {
        Hr[p] = ldws2(sWhh,      jt + c2, p);
        Hz[p] = ldws2(sWhh, 16 + jt + c2, p);
        Hn[p] = ldws2(whhG, 32 + jt + c2, p);
      }
      f32x4 er = {0,0,0,0}, ez = {0,0,0,0}, ei = {0,0,0,0}, eh = {0,0,0,0};
      #pragma unroll
      for (int p = 0; p < 4; ++p) {
        er = mfma8(Hr[p].x, hp[2*p], er);  er = mfma8(Hr[p].y, hp[2*p+1], er);
        ez = mfma8(Hz[p].x, hp[2*p], ez);  ez = mfma8(Hz[p].y, hp[2*p+1], ez);
        eh = mfma8(Hn[p].x, hp[2*p], eh);  eh = mfma8(Hn[p].y, hp[2*p+1], eh);
      }
      if (!GXE) {
        long xv[8];
        #pragma unroll
        for (int kk = 0; kk < 8; ++kk) xv[kk] = ldsF(sxc, kk);
        longx2 Ir[4], Iz[4], In[4];
        #pragma unroll
        for (int p = 0; p < 4; ++p) {
          Ir[p] = ldws2(wihG,      jt + c2, p);
          Iz[p] = ldws2(wihG, 16 + jt + c2, p);
          In[p] = ldws2(wihG, 32 + jt + c2, p);
        }
        #pragma unroll
        for (int p = 0; p < 4; ++p) {
          er = mfma8(Ir[p].x, xv[2*p], er);  er = mfma8(Ir[p].y, xv[2*p+1], er);
          ez = mfma8(Iz[p].x, xv[2*p], ez);  ez = mfma8(Iz[p].y, xv[2*p+1], ez);
          ei = mfma8(In[p].x, xv[2*p], ei);  ei = mfma8(In[p].y, xv[2*p+1], ei);
        }
      }
      float h0, h1, h2, h3;
      if (GXE) {
        f32x2 rlo = pkf32<false>(gx[c2*3+0]), rhi = pkf32<true>(gx[c2*3+0]);
        f32x2 zlo = pkf32<false>(gx[c2*3+1]), zhi = pkf32<true>(gx[c2*3+1]);
        f32x2 nlo = pkf32<false>(gx[c2*3+2]), nhi = pkf32<true>(gx[c2*3+2]);
        f32x4 bn = bnv[c2];
        h0 = gru_h(er[0]+rlo[0], ez[0]+zlo[0], nlo[0], eh[0]+bn[0], heM[c2][0]);
        h1 = gru_h(er[1]+rlo[1], ez[1]+zlo[1], nlo[1], eh[1]+bn[1], heM[c2][1]);
        h2 = gru_h(er[2]+rhi[0], ez[2]+zhi[0], nhi[0], eh[2]+bn[2], heM[c2][2]);
        h3 = gru_h(er[3]+rhi[1], ez[3]+zhi[1], nhi[1], eh[3]+bn[3], heM[c2][3]);
      } else {
        h0 = gru_h(er[0]+brv[c2][0], ez[0]+bzv[c2][0], ei[0]+biv[c2][0], eh[0]+bhv2[c2][0], heM[c2][0]);
        h1 = gru_h(er[1]+brv[c2][1], ez[1]+bzv[c2][1], ei[1]+biv[c2][1], eh[1]+bhv2[c2][1], heM[c2][1]);
        h2 = gru_h(er[2]+brv[c2][2], ez[2]+bzv[c2][2], ei[2]+biv[c2][2], eh[2]+bhv2[c2][2], heM[c2][2]);
        h3 = gru_h(er[3]+brv[c2][3], ez[3]+bzv[c2][3], ei[3]+biv[c2][3], eh[3]+bhv2[c2][3], heM[c2][3]);
      }
      heM[c2][0] = h0; heM[c2][1] = h1; heM[c2][2] = h2; heM[c2][3] = h3;
      unsigned pw = pk2fp8<false>(h0, h1, 0u); pw = pk2fp8<true>(h2, h3, pw);
      stF(hC, cl, j0 + c2 * 16 + rq, pw);
    }
    if (!GXE && i < 511)
      *(u64*)(sx + prv * 4096 + fragoff(threadIdx.x >> 5, threadIdx.x & 31)) = xpre;
    __syncthreads();
  }
  #pragma unroll
  for (int c2 = 0; c2 < 2; ++c2)
    *(f32x4*)(P.henc + (size_t)(dir * 256 + b0 + cl) * 256 + j0 + c2 * 16 + rq) = heM[c2];
}

__global__ __launch_bounds__(512)
__attribute__((amdgpu_waves_per_eu(2, 2)))
void k_main(Params P) {
  extern __shared__ char smem[];
  const int blk = blockIdx.x;
  if (blk < 16) cg_role(P, blk, smem);
  else {
    const int e = blk - 16;
    if (P.useGxe) enc_role<true>(P, e >> 4, (e & 15) << 4, smem);
    else          enc_role<false>(P, e >> 4, (e & 15) << 4, smem);
  }
}

// ---------------------------------------------------------------- k_post
__global__ __launch_bounds__(256) void k_post(Params P) {
  const int blk = blockIdx.x;
  if (blk < 32) {
    __shared__ float red[4];
    float ka = 0.f;
    #pragma unroll 1
    for (int pp = 0; pp < 2; ++pp) {
      int p = blk * 512 + threadIdx.x * 2 + pp;
      int b = p >> 6, l = p & 63;
      float mu = P.b_mu0[l], lv = P.b_lv0[l];
      const float* wm = P.W_mu0 + (size_t)l * 512;
      const float* wl = P.W_lv0 + (size_t)l * 512;
      const float* h0 = P.henc + (size_t)b * 256;
      const float* h1 = P.henc + (size_t)(256 + b) * 256;
      #pragma unroll 4
      for (int k = 0; k < 256; ++k) {
        float hf = h0[k], hb = h1[k];
        mu += hf * wm[k] + hb * wm[256 + k];
        lv += hf * wl[k] + hb * wl[256 + k];
      }
      ka += __expf(lv) + mu * mu - 1.f - lv;
    }
    const int lane = threadIdx.x & 63, wid = threadIdx.x >> 6;
    ka += __shfl_down(ka, 32); ka += __shfl_down(ka, 16); ka += __shfl_down(ka, 8);
    ka += __shfl_down(ka, 4);  ka += __shfl_down(ka, 2);  ka += __shfl_down(ka, 1);
    if (lane == 0) red[wid] = ka;
    __syncthreads();
    if (threadIdx.x == 0) P.klics[blk] = red[0] + red[1] + red[2] + red[3];
  } else {
    const int lane = threadIdx.x & 63, wid = threadIdx.x >> 6;
    const int cl = lane & 15, rq = (lane >> 4) << 2;
    const int gw = (blk - 32) * 4 + wid;
    const size_t r0 = (size_t)gw << 4;
    const float* Fs = P.out + FOUT;
    short8 F0 = ldfrag_f32(Fs + r0 * 64, 64);
    short8 F1 = ldfrag_f32(Fs + r0 * 64 + 32, 64);
    #pragma unroll 1
    for (int ct = 0; ct < 16; ++ct) {
      const int d0 = ct << 4;
      const u16* W = P.wrbf + (size_t)d0 * 64;
      f32x4 a = {0,0,0,0};
      a = MFMA(ldfrag(W, 64), F0, a);
      a = MFMA(ldfrag(W + 32, 64), F1, a);
      f32x4 rb = *(const f32x4*)(P.b_r + d0 + rq);
      f32x4 o;
      o[0] = __expf(a[0] + rb[0]); o[1] = __expf(a[1] + rb[1]);
      o[2] = __expf(a[2] + rb[2]); o[3] = __expf(a[3] + rb[3]);
      *(f32x4*)(P.out + (r0 + cl) * 256 + d0 + rq) = o;
    }
  }
}

__global__ void k_final(Params P) {
  if (threadIdx.x == 0) {
    float s = 0.f, s2 = 0.f;
    for (int i = 0; i < 16; ++i) s += P.klacc[i];
    for (int i = 0; i < 32; ++i) s2 += P.klics[i];
    P.out[RATES_N]     = s2 * (0.5f / 256.f);
    P.out[RATES_N + 1] = s  * (0.5f / (256.f * 512.f));
  }
}

// ---------------------------------------------------------------- launch
extern "C" void kernel_launch(void* const* d_in, const int* in_sizes, int n_in,
                              void* d_out, int out_size, void* d_ws, size_t ws_size,
                              hipStream_t stream) {
  (void)in_sizes; (void)n_in; (void)out_size;
  Params P;
  const float* const* in = (const float* const*)d_in;
  P.x = in[0];      P.eps = in[1];
  P.Wih_ef = in[2]; P.Whh_ef = in[3]; P.bih_ef = in[4]; P.bhh_ef = in[5];
  P.Wih_eb = in[6]; P.Whh_eb = in[7]; P.bih_eb = in[8]; P.bhh_eb = in[9];
  P.W_mu0 = in[10]; P.b_mu0 = in[11]; P.W_lv0 = in[12]; P.b_lv0 = in[13];
  P.Wih_c = in[14]; P.Whh_c = in[15]; P.bih_c = in[16]; P.bhh_c = in[17];
  P.W_cmu = in[18]; P.b_cmu = in[19]; P.W_clv = in[20]; P.b_clv = in[21];
  P.Wih_g = in[22]; P.Whh_g = in[23]; P.bih_g = in[24]; P.bhh_g = in[25];
  P.W_f = in[26];   P.b_f = in[27];   P.W_r = in[28];   P.b_r = in[29];

  char* w = (char*)d_ws;
  size_t off = 0;
  auto take = [&](size_t bytes) -> char* {
    char* r = w + off;
    off = (off + bytes + 255) & ~(size_t)255;
    return r;
  };
  P.Xf8     = (u8*)take(33554432ull);
  P.ebf     = (u16*)take(16777216ull * 2);
  P.wihcbf  = (u16*)take(196608ull * 2);
  P.wihefbf = (u16*)take(196608ull * 2);
  P.wihebbf = (u16*)take(196608ull * 2);
  P.bfc     = (float*)take(768ull * 4);
  P.bfe     = (float*)take(1536ull * 4);
  P.wihef8  = (u8*)take(196608ull);
  P.whhef8  = (u8*)take(196608ull);
  P.wiheb8  = (u8*)take(196608ull);
  P.whheb8  = (u8*)take(196608ull);
  P.whhc8   = (u8*)take(196608ull);
  P.whhg8   = (u8*)take(196608ull);
  P.wihcf8  = (u8*)take(49152ull);
  P.wihg8   = (u8*)take(49152ull);
  P.wf8     = (u8*)take(16384ull);
  P.wcmu8   = (u8*)take(16384ull);
  P.wclv8   = (u8*)take(16384ull);
  P.wrbf    = (u16*)take(16384ull * 2);
  P.cbn     = (float*)take(256ull * 4);
  P.ebn     = (float*)take(512ull * 4);
  P.gb      = (float*)take(1024ull * 4);
  P.hdb     = (float*)take(128ull * 4);
  P.fb2     = (float*)take(64ull * 4);
  P.eb      = (float*)take(2048ull * 4);
  P.henc    = (float*)take(131072ull * 4);
  P.klacc   = (float*)take(64ull * 4);
  P.klics   = (float*)take(64ull * 4);
  size_t gxe_off = (off + 255) & ~(size_t)255;
  P.useGxe = (gxe_off + 2 * GXE_D <= ws_size) ? 1 : 0;
  P.Gxe = P.useGxe ? (u8*)(w + gxe_off) : (u8*)w;
  P.Gxc = (u8*)d_out;
  P.out = (float*)d_out;

  hipLaunchKernelGGL(k_init,  dim3(2048), dim3(256), 0, stream, P);
  hipLaunchKernelGGL(k_gx,    dim3(6144), dim3(512), 131072, stream, P);
  hipLaunchKernelGGL(k_main,  dim3(48),   dim3(512), 158016, stream, P);
  hipLaunchKernelGGL(k_post,  dim3(2080), dim3(256), 0, stream, P);
  hipLaunchKernelGGL(k_final, dim3(1),    dim3(64),  0, stream, P);
}